// Round 1
// baseline (408.274 us; speedup 1.0000x reference)
//
#include <hip/hip_runtime.h>
#include <hip/hip_bf16.h>
#include <math.h>

typedef __attribute__((ext_vector_type(8))) short short8;
typedef __attribute__((ext_vector_type(4))) float f32x4;
typedef __attribute__((address_space(1))) const void CG;
typedef __attribute__((address_space(3))) void LS;

#define LOAD_LDS16(src, dst) __builtin_amdgcn_global_load_lds((CG*)(src), (LS*)(dst), 16, 0, 0)

__device__ __forceinline__ short f2bf(float f) {
  union { float f; unsigned u; } v; v.f = f;
  unsigned r = v.u + 0x7fffu + ((v.u >> 16) & 1u);
  return (short)(r >> 16);
}

// ---------------- transpose + fp32->bf16 convert: Wt[n][k] = W[k][n] ----------------
__global__ __launch_bounds__(256) void transp_f32_bf16(const float* __restrict__ W,
                                                       short* __restrict__ Wt,
                                                       int K, int N) {
  __shared__ short t[32][33];
  int n0 = blockIdx.x << 5, k0 = blockIdx.y << 5;
  int tid = threadIdx.x;
#pragma unroll
  for (int p = 0; p < 4; ++p) {
    int e = tid + (p << 8);
    int r = e >> 5, c = e & 31;
    t[r][c] = f2bf(W[(size_t)(k0 + r) * N + n0 + c]);
  }
  __syncthreads();
#pragma unroll
  for (int p = 0; p < 4; ++p) {
    int e = tid + (p << 8);
    int r = e >> 5, c = e & 31;
    Wt[(size_t)(n0 + r) * K + k0 + c] = t[c][r];
  }
}

// ---------------- LayerNorm (C=768), fp32 in -> bf16 out ----------------
__global__ __launch_bounds__(256) void ln_kernel(const float* __restrict__ x,
                                                 const float* __restrict__ g,
                                                 const float* __restrict__ b,
                                                 short* __restrict__ out) {
  int row = blockIdx.x;
  const float* xr = x + (size_t)row * 768;
  int tid = threadIdx.x;
  float v0 = xr[tid], v1 = xr[tid + 256], v2 = xr[tid + 512];
  float s = v0 + v1 + v2;
  float ss = v0 * v0 + v1 * v1 + v2 * v2;
#pragma unroll
  for (int m = 1; m < 64; m <<= 1) { s += __shfl_xor(s, m); ss += __shfl_xor(ss, m); }
  __shared__ float red[8];
  int w = tid >> 6;
  if ((tid & 63) == 0) { red[w] = s; red[w + 4] = ss; }
  __syncthreads();
  s = red[0] + red[1] + red[2] + red[3];
  ss = red[4] + red[5] + red[6] + red[7];
  float mean = s * (1.0f / 768.0f);
  float var = ss * (1.0f / 768.0f) - mean * mean;
  float rs = rsqrtf(var + 1e-5f);
  short* outr = out + (size_t)row * 768;
  outr[tid]       = f2bf((v0 - mean) * rs * g[tid]       + b[tid]);
  outr[tid + 256] = f2bf((v1 - mean) * rs * g[tid + 256] + b[tid + 256]);
  outr[tid + 512] = f2bf((v2 - mean) * rs * g[tid + 512] + b[tid + 512]);
}

// ---------------- GEMM: C[M,N] = A[M,K] @ Bt[N,K]^T  (bf16 in, fp32 acc) ----------------
// EPI 0: QKV split (Q,K normal [bh,t,d]; V transposed [bh,d,t])
// EPI 1: + resid (fp32) -> fp32 out
// EPI 2: + bias, exact GELU -> bf16 out
// EPI 3: + bias + resid -> fp32 out
template <int EPI>
__global__ __launch_bounds__(256, 2) void gemm_bt(
    const short* __restrict__ A, const short* __restrict__ Bt,
    int M, int N, int K,
    short* __restrict__ outQ, short* __restrict__ outK, short* __restrict__ outVt,
    float* __restrict__ outF, short* __restrict__ outB,
    const float* __restrict__ bias, const float* __restrict__ resid) {
  __shared__ short lA[128 * 32];
  __shared__ short lB[128 * 32];
  int tid = threadIdx.x;
  int lane = tid & 63, w = tid >> 6;
  int li = lane & 15, g = lane >> 4;
  int bm = blockIdx.y << 7, bn = blockIdx.x << 7;
  int wrow = (w >> 1) << 6, wcol = (w & 1) << 6;

  const short* as[2];
  const short* bs[2];
#pragma unroll
  for (int p = 0; p < 2; ++p) {
    int v = tid + (p << 8);
    int row = v >> 2;
    int lc = (v & 3) ^ ((row ^ (row >> 2)) & 3);  // pre-swizzled source chunk
    as[p] = A + (size_t)(bm + row) * K + lc * 8;
    bs[p] = Bt + (size_t)(bn + row) * K + lc * 8;
  }
  char* lAb = (char*)lA;
  char* lBb = (char*)lB;
  int sg = (g ^ ((li ^ (li >> 2)) & 3)) << 3;  // swizzled k-chunk (shorts)

  f32x4 zero = {0.f, 0.f, 0.f, 0.f};
  f32x4 acc[4][4];
#pragma unroll
  for (int i = 0; i < 4; ++i)
#pragma unroll
    for (int j = 0; j < 4; ++j) acc[i][j] = zero;

  for (int k0 = 0; k0 < K; k0 += 32) {
    __syncthreads();
#pragma unroll
    for (int p = 0; p < 2; ++p) {
      LOAD_LDS16(as[p] + k0, lAb + (p << 12) + (w << 10));
      LOAD_LDS16(bs[p] + k0, lBb + (p << 12) + (w << 10));
    }
    __syncthreads();
    short8 af[4], bf[4];
#pragma unroll
    for (int rt = 0; rt < 4; ++rt)
      af[rt] = *(const short8*)&lA[(wrow + rt * 16 + li) * 32 + sg];
#pragma unroll
    for (int ct = 0; ct < 4; ++ct)
      bf[ct] = *(const short8*)&lB[(wcol + ct * 16 + li) * 32 + sg];
#pragma unroll
    for (int rt = 0; rt < 4; ++rt)
#pragma unroll
      for (int ct = 0; ct < 4; ++ct)
        acc[rt][ct] = __builtin_amdgcn_mfma_f32_16x16x32_bf16(af[rt], bf[ct], acc[rt][ct], 0, 0, 0);
  }

#pragma unroll
  for (int rt = 0; rt < 4; ++rt) {
    int mbase = bm + wrow + rt * 16 + g * 4;
#pragma unroll
    for (int ct = 0; ct < 4; ++ct) {
      int n = bn + wcol + ct * 16 + li;
      f32x4 c = acc[rt][ct];
      if (EPI == 0) {
        if (n < 768) {
          int h = n >> 6, d = n & 63;
#pragma unroll
          for (int i = 0; i < 4; ++i) {
            int tok = mbase + i;
            int bb = tok >> 11, t = tok & 2047;
            outQ[((size_t)((bb * 12 + h) * 2048 + t) << 6) + d] = f2bf(c[i]);
          }
        } else if (n < 1536) {
          int nn = n - 768;
          int h = nn >> 6, d = nn & 63;
#pragma unroll
          for (int i = 0; i < 4; ++i) {
            int tok = mbase + i;
            int bb = tok >> 11, t = tok & 2047;
            outK[((size_t)((bb * 12 + h) * 2048 + t) << 6) + d] = f2bf(c[i]);
          }
        } else {
          int nn = n - 1536;
          int h = nn >> 6, d = nn & 63;
          int bb = mbase >> 11, t = mbase & 2047;
          ushort4 pk;
          pk.x = (unsigned short)f2bf(c[0]);
          pk.y = (unsigned short)f2bf(c[1]);
          pk.z = (unsigned short)f2bf(c[2]);
          pk.w = (unsigned short)f2bf(c[3]);
          *(ushort4*)((unsigned short*)outVt + (((size_t)((bb * 12 + h) * 64 + d)) << 11) + t) = pk;
        }
      } else if (EPI == 1) {
#pragma unroll
        for (int i = 0; i < 4; ++i) {
          int m = mbase + i;
          outF[(size_t)m * N + n] = c[i] + resid[(size_t)m * N + n];
        }
      } else if (EPI == 2) {
        float bv = bias[n];
#pragma unroll
        for (int i = 0; i < 4; ++i) {
          int m = mbase + i;
          float xx = c[i] + bv;
          float gel = 0.5f * xx * (1.0f + erff(xx * 0.70710678118654752f));
          outB[(size_t)m * N + n] = f2bf(gel);
        }
      } else {
        float bv = bias[n];
#pragma unroll
        for (int i = 0; i < 4; ++i) {
          int m = mbase + i;
          outF[(size_t)m * N + n] = c[i] + bv + resid[(size_t)m * N + n];
        }
      }
    }
  }
}

// ---------------- causal flash attention ----------------
// grid: (16 q-tiles, 24 bh). block 256 = 4 waves; wave handles 32 q rows.
__global__ __launch_bounds__(256, 2) void attn_kernel(const short* __restrict__ Q,
                                                      const short* __restrict__ Kk,
                                                      const short* __restrict__ Vt,
                                                      short* __restrict__ O) {
  __shared__ short lK[32 * 64];   // [key][dh] swizzled
  __shared__ short lV[64 * 32];   // [dh][key] swizzled
  __shared__ short lP[4][32 * 32];
  int tid = threadIdx.x;
  int lane = tid & 63, w = tid >> 6;
  int li = lane & 15, g = lane >> 4;
  int bh = blockIdx.y;
  int qt = (int)gridDim.x - 1 - (int)blockIdx.x;  // heavy tiles first
  int qbase = (qt << 7) + (w << 5);
  const short* Qb = Q + ((size_t)bh << 17);
  const short* Kb = Kk + ((size_t)bh << 17);
  const short* Vb = Vt + ((size_t)bh << 17);

  short8 qf[2][2];
#pragma unroll
  for (int rt = 0; rt < 2; ++rt)
#pragma unroll
    for (int kc = 0; kc < 2; ++kc)
      qf[rt][kc] = *(const short8*)&Qb[(size_t)(qbase + rt * 16 + li) * 64 + kc * 32 + g * 8];

  f32x4 zero = {0.f, 0.f, 0.f, 0.f};
  f32x4 o[2][4];
  float mrow[2][4], lrow[2][4];
#pragma unroll
  for (int rt = 0; rt < 2; ++rt) {
#pragma unroll
    for (int ct = 0; ct < 4; ++ct) o[rt][ct] = zero;
#pragma unroll
    for (int i = 0; i < 4; ++i) { mrow[rt][i] = -1e30f; lrow[rt][i] = 0.f; }
  }

  int tK_row = tid >> 3;
  int tK_lc = (tid & 7) ^ (tK_row & 7);
  const short* kSrc = Kb + (size_t)tK_row * 64 + tK_lc * 8;
  int tV_row = tid >> 2;
  int tV_lc = (tid & 3) ^ ((tV_row ^ (tV_row >> 2)) & 3);
  const short* vSrc = Vb + (size_t)tV_row * 2048 + tV_lc * 8;

  int sK = li & 7;
  int sV = (li ^ (li >> 2)) & 3;

  int nkt = (qt + 1) << 2;
  const float SCALE = 0.18033688011112042f;  // log2(e)/8

  for (int kt = 0; kt < nkt; ++kt) {
    __syncthreads();
    LOAD_LDS16(kSrc + ((size_t)kt << 11), (char*)lK + (w << 10));
    LOAD_LDS16(vSrc + ((size_t)kt << 5), (char*)lV + (w << 10));
    __syncthreads();

    f32x4 s[2][2];
    s[0][0] = zero; s[0][1] = zero; s[1][0] = zero; s[1][1] = zero;
#pragma unroll
    for (int kc = 0; kc < 2; ++kc)
#pragma unroll
      for (int ct = 0; ct < 2; ++ct) {
        short8 kf = *(const short8*)&lK[(ct * 16 + li) * 64 + ((((kc << 2) | g) ^ sK) << 3)];
#pragma unroll
        for (int rt = 0; rt < 2; ++rt)
          s[rt][ct] = __builtin_amdgcn_mfma_f32_16x16x32_bf16(qf[rt][kc], kf, s[rt][ct], 0, 0, 0);
      }

    int kbase = kt << 5;
#pragma unroll
    for (int rt = 0; rt < 2; ++rt) {
      int qrow0 = qbase + rt * 16 + g * 4;
#pragma unroll
      for (int i = 0; i < 4; ++i) {
        int qrow = qrow0 + i;
#pragma unroll
        for (int ct = 0; ct < 2; ++ct) {
          int kcol = kbase + ct * 16 + li;
          if (kcol > qrow) s[rt][ct][i] = -1e30f;
        }
        float mx = fmaxf(s[rt][0][i], s[rt][1][i]);
        mx = fmaxf(mx, __shfl_xor(mx, 1));
        mx = fmaxf(mx, __shfl_xor(mx, 2));
        mx = fmaxf(mx, __shfl_xor(mx, 4));
        mx = fmaxf(mx, __shfl_xor(mx, 8));
        float mnew = fmaxf(mrow[rt][i], mx);
        float corr = exp2f((mrow[rt][i] - mnew) * SCALE);
        mrow[rt][i] = mnew;
        float p0 = exp2f((s[rt][0][i] - mnew) * SCALE);
        float p1 = exp2f((s[rt][1][i] - mnew) * SCALE);
        s[rt][0][i] = p0;
        s[rt][1][i] = p1;
        float rsum = p0 + p1;
        rsum += __shfl_xor(rsum, 1);
        rsum += __shfl_xor(rsum, 2);
        rsum += __shfl_xor(rsum, 4);
        rsum += __shfl_xor(rsum, 8);
        lrow[rt][i] = lrow[rt][i] * corr + rsum;
#pragma unroll
        for (int ct = 0; ct < 4; ++ct) o[rt][ct][i] *= corr;
      }
    }

    // write P (bf16) to per-wave swizzled LDS
    unsigned short* lPw = (unsigned short*)lP[w];
#pragma unroll
    for (int rt = 0; rt < 2; ++rt)
#pragma unroll
      for (int ct = 0; ct < 2; ++ct)
#pragma unroll
        for (int i = 0; i < 4; ++i) {
          int row = rt * 16 + g * 4 + i;
          int col = ct * 16 + li;
          int chunk = (col >> 3) ^ ((i ^ g) & 3);
          lPw[(row << 5) + (chunk << 3) + (col & 7)] = (unsigned short)f2bf(s[rt][ct][i]);
        }
    __syncthreads();

    short8 vf[4];
#pragma unroll
    for (int ct = 0; ct < 4; ++ct)
      vf[ct] = *(const short8*)&lV[((ct * 16 + li) << 5) + ((g ^ sV) << 3)];
#pragma unroll
    for (int rt = 0; rt < 2; ++rt) {
      short8 pf = *(const short8*)&lP[w][((rt * 16 + li) << 5) + ((g ^ sV) << 3)];
#pragma unroll
      for (int ct = 0; ct < 4; ++ct)
        o[rt][ct] = __builtin_amdgcn_mfma_f32_16x16x32_bf16(pf, vf[ct], o[rt][ct], 0, 0, 0);
    }
  }

  int b = bh / 12, h = bh % 12;
#pragma unroll
  for (int rt = 0; rt < 2; ++rt)
#pragma unroll
    for (int i = 0; i < 4; ++i) {
      float inv = 1.0f / lrow[rt][i];
      int t = qbase + rt * 16 + g * 4 + i;
      size_t base = ((size_t)(b * 2048 + t)) * 768 + h * 64;
#pragma unroll
      for (int ct = 0; ct < 4; ++ct)
        O[base + ct * 16 + li] = f2bf(o[rt][ct][i] * inv);
    }
}

// ---------------- launch ----------------
extern "C" void kernel_launch(void* const* d_in, const int* in_sizes, int n_in,
                              void* d_out, int out_size, void* d_ws, size_t ws_size,
                              hipStream_t stream) {
  const float* x     = (const float*)d_in[0];
  const float* w_qkv = (const float*)d_in[1];
  const float* w_out = (const float*)d_in[2];
  const float* ln1g  = (const float*)d_in[3];
  const float* ln1b  = (const float*)d_in[4];
  const float* ln2g  = (const float*)d_in[5];
  const float* ln2b  = (const float*)d_in[6];
  const float* w1    = (const float*)d_in[7];
  const float* b1    = (const float*)d_in[8];
  const float* w2    = (const float*)d_in[9];
  const float* b2    = (const float*)d_in[10];
  float* out = (float*)d_out;
  char* ws = (char*)d_ws;

  short* wqkvT = (short*)(ws + 0);         // 2304x768 bf16
  short* woutT = (short*)(ws + 3538944);   // 768x768
  short* w1T   = (short*)(ws + 4718592);   // 3072x768
  short* w2T   = (short*)(ws + 9437184);   // 768x3072
  short* qb    = (short*)(ws + 14155776);  // [2,12,2048,64]
  short* kb    = (short*)(ws + 20447232);
  short* vtb   = (short*)(ws + 26738688);  // [2,12,64,2048]
  short* attnb = (short*)(ws + 33030144);  // [4096,768]
  short* ab    = qb;                        // FF1 out aliases q..attn (25.17MB)
  short* xnb   = (short*)(ws + 39321600);  // LN out bf16 [4096,768]
  float* x2b   = (float*)(ws + 45613056);  // fp32 [4096,768]

  transp_f32_bf16<<<dim3(72, 24), 256, 0, stream>>>(w_qkv, wqkvT, 768, 2304);
  transp_f32_bf16<<<dim3(24, 24), 256, 0, stream>>>(w_out, woutT, 768, 768);
  transp_f32_bf16<<<dim3(96, 24), 256, 0, stream>>>(w1, w1T, 768, 3072);
  transp_f32_bf16<<<dim3(24, 96), 256, 0, stream>>>(w2, w2T, 3072, 768);

  ln_kernel<<<dim3(4096), 256, 0, stream>>>(x, ln1g, ln1b, xnb);

  gemm_bt<0><<<dim3(18, 32), 256, 0, stream>>>(xnb, wqkvT, 4096, 2304, 768,
                                               qb, kb, vtb, nullptr, nullptr, nullptr, nullptr);

  attn_kernel<<<dim3(16, 24), 256, 0, stream>>>(qb, kb, vtb, attnb);

  gemm_bt<1><<<dim3(6, 32), 256, 0, stream>>>(attnb, woutT, 4096, 768, 768,
                                              nullptr, nullptr, nullptr, x2b, nullptr, nullptr, x);

  ln_kernel<<<dim3(4096), 256, 0, stream>>>(x2b, ln2g, ln2b, xnb);

  gemm_bt<2><<<dim3(24, 32), 256, 0, stream>>>(xnb, w1T, 4096, 3072, 768,
                                               nullptr, nullptr, nullptr, nullptr, ab, b1, nullptr);

  gemm_bt<3><<<dim3(6, 32), 256, 0, stream>>>(ab, w2T, 4096, 768, 3072,
                                              nullptr, nullptr, nullptr, out, nullptr, b2, x2b);
}

// Round 2
// 271.740 us; speedup vs baseline: 1.5024x; 1.5024x over previous
//
#include <hip/hip_runtime.h>
#include <hip/hip_bf16.h>
#include <math.h>

typedef __attribute__((ext_vector_type(8))) short short8;
typedef __attribute__((ext_vector_type(4))) float f32x4;
typedef __attribute__((address_space(1))) const void CG;
typedef __attribute__((address_space(3))) void LS;

#define LOAD_LDS16(src, dst) __builtin_amdgcn_global_load_lds((CG*)(src), (LS*)(dst), 16, 0, 0)

__device__ __forceinline__ short f2bf(float f) {
  union { float f; unsigned u; } v; v.f = f;
  unsigned r = v.u + 0x7fffu + ((v.u >> 16) & 1u);
  return (short)(r >> 16);
}

// ---------------- transpose + fp32->bf16 convert: Wt[n][k] = W[k][n] ----------------
__global__ __launch_bounds__(256) void transp_f32_bf16(const float* __restrict__ W,
                                                       short* __restrict__ Wt,
                                                       int K, int N) {
  __shared__ short t[32][33];
  int n0 = blockIdx.x << 5, k0 = blockIdx.y << 5;
  int tid = threadIdx.x;
#pragma unroll
  for (int p = 0; p < 4; ++p) {
    int e = tid + (p << 8);
    int r = e >> 5, c = e & 31;
    t[r][c] = f2bf(W[(size_t)(k0 + r) * N + n0 + c]);
  }
  __syncthreads();
#pragma unroll
  for (int p = 0; p < 4; ++p) {
    int e = tid + (p << 8);
    int r = e >> 5, c = e & 31;
    Wt[(size_t)(n0 + r) * K + k0 + c] = t[c][r];
  }
}

// ---------------- LayerNorm (C=768), fp32 in -> bf16 out ----------------
__global__ __launch_bounds__(256) void ln_kernel(const float* __restrict__ x,
                                                 const float* __restrict__ g,
                                                 const float* __restrict__ b,
                                                 short* __restrict__ out) {
  int row = blockIdx.x;
  const float* xr = x + (size_t)row * 768;
  int tid = threadIdx.x;
  float v0 = xr[tid], v1 = xr[tid + 256], v2 = xr[tid + 512];
  float s = v0 + v1 + v2;
  float ss = v0 * v0 + v1 * v1 + v2 * v2;
#pragma unroll
  for (int m = 1; m < 64; m <<= 1) { s += __shfl_xor(s, m); ss += __shfl_xor(ss, m); }
  __shared__ float red[8];
  int w = tid >> 6;
  if ((tid & 63) == 0) { red[w] = s; red[w + 4] = ss; }
  __syncthreads();
  s = red[0] + red[1] + red[2] + red[3];
  ss = red[4] + red[5] + red[6] + red[7];
  float mean = s * (1.0f / 768.0f);
  float var = ss * (1.0f / 768.0f) - mean * mean;
  float rs = rsqrtf(var + 1e-5f);
  short* outr = out + (size_t)row * 768;
  outr[tid]       = f2bf((v0 - mean) * rs * g[tid]       + b[tid]);
  outr[tid + 256] = f2bf((v1 - mean) * rs * g[tid + 256] + b[tid + 256]);
  outr[tid + 512] = f2bf((v2 - mean) * rs * g[tid + 512] + b[tid + 512]);
}

// ---------------- GEMM: C[M,N] = A[M,K] @ Bt[N,K]^T  (bf16 in, fp32 acc) ----------------
template <int EPI>
__global__ __launch_bounds__(256, 2) void gemm_bt(
    const short* __restrict__ A, const short* __restrict__ Bt,
    int M, int N, int K,
    short* __restrict__ outQ, short* __restrict__ outK, short* __restrict__ outVt,
    float* __restrict__ outF, short* __restrict__ outB,
    const float* __restrict__ bias, const float* __restrict__ resid) {
  __shared__ short lA[128 * 32];
  __shared__ short lB[128 * 32];
  int tid = threadIdx.x;
  int lane = tid & 63, w = tid >> 6;
  int li = lane & 15, g = lane >> 4;
  int bm = blockIdx.y << 7, bn = blockIdx.x << 7;
  int wrow = (w >> 1) << 6, wcol = (w & 1) << 6;

  const short* as[2];
  const short* bs[2];
#pragma unroll
  for (int p = 0; p < 2; ++p) {
    int v = tid + (p << 8);
    int row = v >> 2;
    int lc = (v & 3) ^ ((row ^ (row >> 2)) & 3);
    as[p] = A + (size_t)(bm + row) * K + lc * 8;
    bs[p] = Bt + (size_t)(bn + row) * K + lc * 8;
  }
  char* lAb = (char*)lA;
  char* lBb = (char*)lB;
  int sg = (g ^ ((li ^ (li >> 2)) & 3)) << 3;

  f32x4 zero = {0.f, 0.f, 0.f, 0.f};
  f32x4 acc[4][4];
#pragma unroll
  for (int i = 0; i < 4; ++i)
#pragma unroll
    for (int j = 0; j < 4; ++j) acc[i][j] = zero;

  for (int k0 = 0; k0 < K; k0 += 32) {
    __syncthreads();
#pragma unroll
    for (int p = 0; p < 2; ++p) {
      LOAD_LDS16(as[p] + k0, lAb + (p << 12) + (w << 10));
      LOAD_LDS16(bs[p] + k0, lBb + (p << 12) + (w << 10));
    }
    __syncthreads();
    short8 af[4], bf[4];
#pragma unroll
    for (int rt = 0; rt < 4; ++rt)
      af[rt] = *(const short8*)&lA[(wrow + rt * 16 + li) * 32 + sg];
#pragma unroll
    for (int ct = 0; ct < 4; ++ct)
      bf[ct] = *(const short8*)&lB[(wcol + ct * 16 + li) * 32 + sg];
#pragma unroll
    for (int rt = 0; rt < 4; ++rt)
#pragma unroll
      for (int ct = 0; ct < 4; ++ct)
        acc[rt][ct] = __builtin_amdgcn_mfma_f32_16x16x32_bf16(af[rt], bf[ct], acc[rt][ct], 0, 0, 0);
  }

#pragma unroll
  for (int rt = 0; rt < 4; ++rt) {
    int mbase = bm + wrow + rt * 16 + g * 4;
#pragma unroll
    for (int ct = 0; ct < 4; ++ct) {
      int n = bn + wcol + ct * 16 + li;
      f32x4 c = acc[rt][ct];
      if (EPI == 0) {
        if (n < 768) {
          int h = n >> 6, d = n & 63;
#pragma unroll
          for (int i = 0; i < 4; ++i) {
            int tok = mbase + i;
            int bb = tok >> 11, t = tok & 2047;
            outQ[((size_t)((bb * 12 + h) * 2048 + t) << 6) + d] = f2bf(c[i]);
          }
        } else if (n < 1536) {
          int nn = n - 768;
          int h = nn >> 6, d = nn & 63;
#pragma unroll
          for (int i = 0; i < 4; ++i) {
            int tok = mbase + i;
            int bb = tok >> 11, t = tok & 2047;
            outK[((size_t)((bb * 12 + h) * 2048 + t) << 6) + d] = f2bf(c[i]);
          }
        } else {
          int nn = n - 1536;
          int h = nn >> 6, d = nn & 63;
          int bb = mbase >> 11, t = mbase & 2047;
          ushort4 pk;
          pk.x = (unsigned short)f2bf(c[0]);
          pk.y = (unsigned short)f2bf(c[1]);
          pk.z = (unsigned short)f2bf(c[2]);
          pk.w = (unsigned short)f2bf(c[3]);
          *(ushort4*)((unsigned short*)outVt + (((size_t)((bb * 12 + h) * 64 + d)) << 11) + t) = pk;
        }
      } else if (EPI == 1) {
#pragma unroll
        for (int i = 0; i < 4; ++i) {
          int m = mbase + i;
          outF[(size_t)m * N + n] = c[i] + resid[(size_t)m * N + n];
        }
      } else if (EPI == 2) {
        float bv = bias[n];
#pragma unroll
        for (int i = 0; i < 4; ++i) {
          int m = mbase + i;
          float xx = c[i] + bv;
          float gel = 0.5f * xx * (1.0f + erff(xx * 0.70710678118654752f));
          outB[(size_t)m * N + n] = f2bf(gel);
        }
      } else {
        float bv = bias[n];
#pragma unroll
        for (int i = 0; i < 4; ++i) {
          int m = mbase + i;
          outF[(size_t)m * N + n] = c[i] + bv + resid[(size_t)m * N + n];
        }
      }
    }
  }
}

// ---------------- causal flash attention v2 ----------------
// grid: (16 q-tiles, 24 bh). block 256 = 4 waves; wave owns 32 q rows.
// KVBLK=64, double-buffered K/V staged via global_load_lds, 1 barrier/tile,
// per-16-row-tile max + defer-rescale (THR=8), row-sum via ones-MFMA.
__global__ __launch_bounds__(256, 3) void attn_kernel(const short* __restrict__ Q,
                                                      const short* __restrict__ Kk,
                                                      const short* __restrict__ Vt,
                                                      short* __restrict__ O) {
  __shared__ short lK[2][64 * 64];   // [key][dh], chunk^=(key&7) swizzle
  __shared__ short lV[2][64 * 64];   // [dh][key], chunk^=(dh&7)  swizzle
  __shared__ short lP[4][32 * 64];   // per-wave P, chunk^=(row&7) swizzle
  int tid = threadIdx.x;
  int lane = tid & 63, w = tid >> 6;
  int li = lane & 15, g = lane >> 4;
  int bh = blockIdx.y;
  int qt = (int)gridDim.x - 1 - (int)blockIdx.x;  // heavy tiles first
  int qbase = (qt << 7) + (w << 5);
  const short* Qb = Q + ((size_t)bh << 17);
  const short* Kb = Kk + ((size_t)bh << 17);
  const short* Vb = Vt + ((size_t)bh << 17);

  short8 qf[2][2];
#pragma unroll
  for (int rt = 0; rt < 2; ++rt)
#pragma unroll
    for (int kc = 0; kc < 2; ++kc)
      qf[rt][kc] = *(const short8*)&Qb[(size_t)(qbase + rt * 16 + li) * 64 + kc * 32 + g * 8];

  // staging source pointers: chunk c -> row=c>>3, physchunk=c&7 holds global chunk (c&7)^(row&7)
  int r0 = tid >> 3, s0 = (tid & 7) ^ (r0 & 7);
  int r1 = r0 + 32,  s1 = (tid & 7) ^ (r1 & 7);
  const short* kS0 = Kb + r0 * 64 + s0 * 8;
  const short* kS1 = Kb + r1 * 64 + s1 * 8;
  const short* vS0 = Vb + (size_t)r0 * 2048 + s0 * 8;
  const short* vS1 = Vb + (size_t)r1 * 2048 + s1 * 8;

#define STAGE(buf, kt)                                                        \
  do {                                                                        \
    LOAD_LDS16(kS0 + (size_t)(kt) * 4096, (char*)lK[buf] + (w << 10));        \
    LOAD_LDS16(kS1 + (size_t)(kt) * 4096, (char*)lK[buf] + 4096 + (w << 10)); \
    LOAD_LDS16(vS0 + (size_t)(kt) * 64,   (char*)lV[buf] + (w << 10));        \
    LOAD_LDS16(vS1 + (size_t)(kt) * 64,   (char*)lV[buf] + 4096 + (w << 10)); \
  } while (0)

  const short8 kOnes = {0x3F80, 0x3F80, 0x3F80, 0x3F80, 0x3F80, 0x3F80, 0x3F80, 0x3F80};
  f32x4 zero = {0.f, 0.f, 0.f, 0.f};
  f32x4 o[2][4];
  f32x4 lrow[2];
  float mrow[2] = {-1e30f, -1e30f};
#pragma unroll
  for (int rt = 0; rt < 2; ++rt) {
    lrow[rt] = zero;
#pragma unroll
    for (int ct = 0; ct < 4; ++ct) o[rt][ct] = zero;
  }

  int diagKt = qbase >> 6;
  int nkt = (qt << 1) + 2;
  const float SCALE = 0.18033688011112042f;  // log2(e)/8
  int sw = li & 7;

  STAGE(0, 0);

  for (int kt = 0; kt < nkt; ++kt) {
    int cur = kt & 1;
    __syncthreads();                       // drains staged loads for buf[cur]
    if (kt + 1 < nkt) STAGE(cur ^ 1, kt + 1);  // prefetch next tile (in flight until next barrier)

    if (kt <= diagKt) {
      const short* Kc = lK[cur];
      const short* Vc = lV[cur];

      // ---- QK^T: S[32 q][64 k] ----
      f32x4 s[2][4];
#pragma unroll
      for (int rt = 0; rt < 2; ++rt)
#pragma unroll
        for (int ct = 0; ct < 4; ++ct) s[rt][ct] = zero;
#pragma unroll
      for (int kc = 0; kc < 2; ++kc)
#pragma unroll
        for (int ct = 0; ct < 4; ++ct) {
          short8 kf = *(const short8*)&Kc[(ct * 16 + li) * 64 + ((((kc << 2) | g) ^ sw) << 3)];
#pragma unroll
          for (int rt = 0; rt < 2; ++rt)
            s[rt][ct] = __builtin_amdgcn_mfma_f32_16x16x32_bf16(qf[rt][kc], kf, s[rt][ct], 0, 0, 0);
        }

      // ---- causal mask (diagonal tile only) ----
      if (kt == diagKt) {
        int kbase = kt << 6;
#pragma unroll
        for (int rt = 0; rt < 2; ++rt) {
          int qrow0 = qbase + rt * 16 + g * 4;
#pragma unroll
          for (int ct = 0; ct < 4; ++ct) {
            int kcol = kbase + ct * 16 + li;
#pragma unroll
            for (int i = 0; i < 4; ++i)
              if (kcol > qrow0 + i) s[rt][ct][i] = -1e30f;
          }
        }
      }

      // ---- per-16-row-tile max, defer-rescale, P -> LDS ----
      unsigned short* Pw = (unsigned short*)lP[w];
#pragma unroll
      for (int rt = 0; rt < 2; ++rt) {
        float tm = s[rt][0][0];
#pragma unroll
        for (int ct = 0; ct < 4; ++ct)
#pragma unroll
          for (int i = 0; i < 4; ++i) tm = fmaxf(tm, s[rt][ct][i]);
#pragma unroll
        for (int m2 = 1; m2 < 64; m2 <<= 1) tm = fmaxf(tm, __shfl_xor(tm, m2));
        if (tm > mrow[rt] + 8.0f) {  // wave-uniform branch
          float corr = exp2f((mrow[rt] - tm) * SCALE);
          mrow[rt] = tm;
#pragma unroll
          for (int i = 0; i < 4; ++i) lrow[rt][i] *= corr;
#pragma unroll
          for (int ct = 0; ct < 4; ++ct)
#pragma unroll
            for (int i = 0; i < 4; ++i) o[rt][ct][i] *= corr;
        }
#pragma unroll
        for (int ct = 0; ct < 4; ++ct)
#pragma unroll
          for (int i = 0; i < 4; ++i) {
            float p = exp2f((s[rt][ct][i] - mrow[rt]) * SCALE);
            int row = rt * 16 + (g << 2) + i;
            int col = (ct << 4) + li;
            int ch = (col >> 3) ^ (row & 7);
            Pw[(row << 6) + (ch << 3) + (col & 7)] = (unsigned short)f2bf(p);
          }
      }

      // ---- PV + row-sum via ones-MFMA (no extra barrier: lP is per-wave) ----
      f32x4 psum[2];
      psum[0] = zero; psum[1] = zero;
#pragma unroll
      for (int kc = 0; kc < 2; ++kc) {
        short8 vf[4];
#pragma unroll
        for (int ct = 0; ct < 4; ++ct)
          vf[ct] = *(const short8*)&Vc[(ct * 16 + li) * 64 + ((((kc << 2) | g) ^ sw) << 3)];
#pragma unroll
        for (int rt = 0; rt < 2; ++rt) {
          short8 pf = *(const short8*)&lP[w][(rt * 16 + li) * 64 + ((((kc << 2) | g) ^ sw) << 3)];
#pragma unroll
          for (int ct = 0; ct < 4; ++ct)
            o[rt][ct] = __builtin_amdgcn_mfma_f32_16x16x32_bf16(pf, vf[ct], o[rt][ct], 0, 0, 0);
          psum[rt] = __builtin_amdgcn_mfma_f32_16x16x32_bf16(pf, kOnes, psum[rt], 0, 0, 0);
        }
      }
#pragma unroll
      for (int rt = 0; rt < 2; ++rt)
#pragma unroll
        for (int i = 0; i < 4; ++i) lrow[rt][i] += psum[rt][i];
    }
  }
#undef STAGE

  int b = bh / 12, h = bh % 12;
#pragma unroll
  for (int rt = 0; rt < 2; ++rt)
#pragma unroll
    for (int i = 0; i < 4; ++i) {
      float inv = 1.0f / lrow[rt][i];
      int t = qbase + rt * 16 + g * 4 + i;
      size_t base = ((size_t)(b * 2048 + t)) * 768 + h * 64;
#pragma unroll
      for (int ct = 0; ct < 4; ++ct)
        O[base + ct * 16 + li] = f2bf(o[rt][ct][i] * inv);
    }
}

// ---------------- launch ----------------
extern "C" void kernel_launch(void* const* d_in, const int* in_sizes, int n_in,
                              void* d_out, int out_size, void* d_ws, size_t ws_size,
                              hipStream_t stream) {
  const float* x     = (const float*)d_in[0];
  const float* w_qkv = (const float*)d_in[1];
  const float* w_out = (const float*)d_in[2];
  const float* ln1g  = (const float*)d_in[3];
  const float* ln1b  = (const float*)d_in[4];
  const float* ln2g  = (const float*)d_in[5];
  const float* ln2b  = (const float*)d_in[6];
  const float* w1    = (const float*)d_in[7];
  const float* b1    = (const float*)d_in[8];
  const float* w2    = (const float*)d_in[9];
  const float* b2    = (const float*)d_in[10];
  float* out = (float*)d_out;
  char* ws = (char*)d_ws;

  short* wqkvT = (short*)(ws + 0);         // 2304x768 bf16
  short* woutT = (short*)(ws + 3538944);   // 768x768
  short* w1T   = (short*)(ws + 4718592);   // 3072x768
  short* w2T   = (short*)(ws + 9437184);   // 768x3072
  short* qb    = (short*)(ws + 14155776);  // [2,12,2048,64]
  short* kb    = (short*)(ws + 20447232);
  short* vtb   = (short*)(ws + 26738688);  // [2,12,64,2048]
  short* attnb = (short*)(ws + 33030144);  // [4096,768]
  short* ab    = qb;                        // FF1 out aliases q..attn
  short* xnb   = (short*)(ws + 39321600);  // LN out bf16 [4096,768]
  float* x2b   = (float*)(ws + 45613056);  // fp32 [4096,768]

  transp_f32_bf16<<<dim3(72, 24), 256, 0, stream>>>(w_qkv, wqkvT, 768, 2304);
  transp_f32_bf16<<<dim3(24, 24), 256, 0, stream>>>(w_out, woutT, 768, 768);
  transp_f32_bf16<<<dim3(96, 24), 256, 0, stream>>>(w1, w1T, 768, 3072);
  transp_f32_bf16<<<dim3(24, 96), 256, 0, stream>>>(w2, w2T, 3072, 768);

  ln_kernel<<<dim3(4096), 256, 0, stream>>>(x, ln1g, ln1b, xnb);

  gemm_bt<0><<<dim3(18, 32), 256, 0, stream>>>(xnb, wqkvT, 4096, 2304, 768,
                                               qb, kb, vtb, nullptr, nullptr, nullptr, nullptr);

  attn_kernel<<<dim3(16, 24), 256, 0, stream>>>(qb, kb, vtb, attnb);

  gemm_bt<1><<<dim3(6, 32), 256, 0, stream>>>(attnb, woutT, 4096, 768, 768,
                                              nullptr, nullptr, nullptr, x2b, nullptr, nullptr, x);

  ln_kernel<<<dim3(4096), 256, 0, stream>>>(x2b, ln2g, ln2b, xnb);

  gemm_bt<2><<<dim3(24, 32), 256, 0, stream>>>(xnb, w1T, 4096, 3072, 768,
                                               nullptr, nullptr, nullptr, nullptr, ab, b1, nullptr);

  gemm_bt<3><<<dim3(6, 32), 256, 0, stream>>>(ab, w2T, 4096, 768, 3072,
                                              nullptr, nullptr, nullptr, out, nullptr, b2, x2b);
}